// Round 10
// baseline (1155.485 us; speedup 1.0000x reference)
//
#include <hip/hip_runtime.h>
#include <hip/hip_bf16.h>
#include <stdint.h>

// out[b,t,k,f] = sum_d x[b,t,d] * (qw[k,d,f]-qz[k,d/128,f])*sc[k,d/128,f]
// Stage 1: FRAGMENT-LINEAR bf16 panels in d_ws at 32-K granularity:
//   panel32 = [128 rows][32 k] = 8KB = 8 fragments of 1KB (frag = rb*2+ks);
//   fragment byte l*16 = row rb*32+(l&31), k = ks*16+(l>>5)*8 .. +8
//   (lane l's mfma_32x32x16 operand slice). LDS read = base + lane*16.
// Stage 2: 256x256 GEMM, BK=32 tiles, QUAD-buffered LDS (4 x 32KB),
//   ONE s_barrier per tile, stage tile T+2 during tile T (2-tile lead),
//   vmcnt(4) at tile end (retires exactly T+1's 4 loads - T4 counted-vmcnt),
//   no lgkm asm inside the tile: compiler's counted lgkmcnt overlaps the
//   12 ds_reads with the 16 MFMAs (m97-verified behavior).
// R9 lesson: 16 barriers/K-tile-pair lockstep all waves (barrier-ramp wall);
// R6 lesson: removing barriers only works with counted vmcnt + >=1-tile lead.

typedef __attribute__((ext_vector_type(8))) short bf16x8;
typedef __attribute__((ext_vector_type(16))) float f32x16;
typedef __attribute__((ext_vector_type(4))) float f32x4;

static constexpr int Dd = 4096, Ff = 8192;
static constexpr int M = 8192, NTOT = 16384;
static constexpr int NKT2 = Dd / 32;      // 128 K-tiles of 32
static constexpr int NMB = M / 256;       // 32
static constexpr int NNB = NTOT / 256;    // 64

__device__ __forceinline__ short f2bf(float f) {
    __hip_bfloat16 h = __float2bfloat16(f);
    return *reinterpret_cast<short*>(&h);
}

// fragment-linear byte offset within an 8KB panel32: row r (0..127),
// 8-elem k-group cb (0..3; k = cb*8..+8)
__device__ __forceinline__ int frag_off32(int r, int cb) {
    const int rb = r >> 5, ks = cb >> 1, kh = cb & 1;
    return ((rb * 2 + ks) << 10) + (((r & 31) + 32 * kh) << 4);
}

// ---------------- Stage 1a: x fp32 -> fragment-linear bf16 A-panel32s ----------------
__global__ __launch_bounds__(256) void xcvt(const float* __restrict__ x,
                                            char* __restrict__ Xw) {
    const int bid = blockIdx.x;             // h*128 + kt2, h in [0,64)
    const int h = bid >> 7, kt2 = bid & 127;
    const int t = threadIdx.x;
    const int r = t >> 1, seg = t & 1;      // seg: k 0-15 | 16-31
    const float* src = x + ((size_t)(h * 128 + r)) * Dd + kt2 * 32 + seg * 16;
    char* panel = Xw + ((size_t)bid << 13);
    #pragma unroll
    for (int jj = 0; jj < 2; ++jj) {
        float4 v0 = *reinterpret_cast<const float4*>(src + jj * 8);
        float4 v1 = *reinterpret_cast<const float4*>(src + jj * 8 + 4);
        union { short s[8]; bf16x8 v; } u;
        u.s[0] = f2bf(v0.x); u.s[1] = f2bf(v0.y); u.s[2] = f2bf(v0.z); u.s[3] = f2bf(v0.w);
        u.s[4] = f2bf(v1.x); u.s[5] = f2bf(v1.y); u.s[6] = f2bf(v1.z); u.s[7] = f2bf(v1.w);
        const int cb = seg * 2 + jj;        // k = cb*8 .. +8
        *reinterpret_cast<bf16x8*>(panel + frag_off32(r, cb)) = u.v;
    }
}

// ---------------- Stage 1b: dequant int4 -> fragment-linear bf16 B^T panel32s ----------------
__global__ __launch_bounds__(256) void wdq(const int* __restrict__ qw,
                                           const int* __restrict__ qz,
                                           const float* __restrict__ sc,
                                           char* __restrict__ Ww) {
    const int bid = blockIdx.x;             // fh*128 + kt2, fh in [0,128)
    const int fh = bid >> 7, kt2 = bid & 127;
    const int t = threadIdx.x;
    const int r = t & 127, dh = t >> 7;     // dh: d 0-15 | 16-31
    const int n = fh * 128 + r;
    const int k = n >> 13, f = n & 8191;
    const int g = kt2 >> 2;                 // quant group (128 d = 4 kt2)
    const int   zv = qz[((size_t)k * 32 + g) * Ff + f];
    const float sv = sc[((size_t)k * 32 + g) * Ff + f];
    const int* qp = qw + ((size_t)(k * Dd + kt2 * 32 + dh * 16)) * Ff + f;
    char* panel = Ww + ((size_t)bid << 13);
    #pragma unroll
    for (int jj = 0; jj < 2; ++jj) {
        union { short s[8]; bf16x8 v; } u;
        #pragma unroll
        for (int e = 0; e < 8; ++e) {
            int q = qp[(size_t)(jj * 8 + e) * Ff];
            u.s[e] = f2bf((float)(q - zv) * sv);
        }
        const int cb = dh * 2 + jj;         // k = cb*8 .. +8
        *reinterpret_cast<bf16x8*>(panel + frag_off32(r, cb)) = u.v;
    }
}

// ---------------- Stage 2: 256x256 GEMM, quad-buffer, 1 barrier/tile ----------------
#define APAN32(H, KT2) (Xw + (((size_t)(H) * 128 + (KT2)) << 13))
#define BPAN32(H, KT2) (Ww + (((size_t)(H) * 128 + (KT2)) << 13))

#define GLL(GP, LP)                                                                \
    __builtin_amdgcn_global_load_lds(                                              \
        (const __attribute__((address_space(1))) void*)(GP),                       \
        (__attribute__((address_space(3))) void*)(LP), 16, 0, 0)

// stage one 32-K tile (4 x 8KB regions = 4 instructions)
#define STAGE_TILE(KT2, BUF) do {                                                  \
    GLL(APAN32(bm2,     (KT2)) + woff16, (BUF) +     0 + woffu);                   \
    GLL(APAN32(bm2 + 1, (KT2)) + woff16, (BUF) +  8192 + woffu);                   \
    GLL(BPAN32(bn2,     (KT2)) + woff16, (BUF) + 16384 + woffu);                   \
    GLL(BPAN32(bn2 + 1, (KT2)) + woff16, (BUF) + 24576 + woffu);                   \
} while (0)

#define SB0() __builtin_amdgcn_sched_barrier(0)

// one 32-K tile: read 12 frags from BUFR, 16 MFMA, stage KT2+2 into BUFS,
// counted vmcnt, single barrier. No internal sched walls (compiler overlaps).
#define BODY(KT2, BUFR, DOST, BUFS) do {                                           \
    if (DOST) STAGE_TILE((KT2) + 2, BUFS);                                         \
    bf16x8 a[8], b[4];                                                             \
    _Pragma("unroll")                                                              \
    for (int mb = 0; mb < 4; ++mb)                                                 \
        _Pragma("unroll")                                                          \
        for (int ks = 0; ks < 2; ++ks)                                             \
            a[mb * 2 + ks] = *reinterpret_cast<const bf16x8*>(                     \
                (BUFR) + aoff + (mb * 2 + ks) * 1024);                             \
    _Pragma("unroll")                                                              \
    for (int nf = 0; nf < 2; ++nf)                                                 \
        _Pragma("unroll")                                                          \
        for (int ks = 0; ks < 2; ++ks)                                             \
            b[nf * 2 + ks] = *reinterpret_cast<const bf16x8*>(                     \
                (BUFR) + boff + nf * 2048 + ks * 1024);                            \
    _Pragma("unroll")                                                              \
    for (int ks = 0; ks < 2; ++ks)                                                 \
        _Pragma("unroll")                                                          \
        for (int mb = 0; mb < 4; ++mb)                                             \
            _Pragma("unroll")                                                      \
            for (int nf = 0; nf < 2; ++nf)                                         \
                acc[mb * 2 + nf] = __builtin_amdgcn_mfma_f32_32x32x16_bf16(        \
                    a[mb * 2 + ks], b[nf * 2 + ks], acc[mb * 2 + nf], 0, 0, 0);    \
    if (DOST) asm volatile("s_waitcnt vmcnt(4)" ::: "memory");                     \
    else      asm volatile("s_waitcnt vmcnt(0)" ::: "memory");                     \
    SB0();                                                                         \
    __builtin_amdgcn_s_barrier();                                                  \
    SB0();                                                                         \
} while (0)

__global__ __launch_bounds__(512, 2) void gemm256(const char* __restrict__ Xw,
                                                  const char* __restrict__ Ww,
                                                  float* __restrict__ out) {
    __shared__ char lds[131072];
    char* const L0 = lds;
    char* const L1 = lds + 32768;
    char* const L2 = lds + 65536;
    char* const L3 = lds + 98304;

    const int t = threadIdx.x;
    const int wave = t >> 6, lane = t & 63;
    const int wm = wave >> 2, wn = wave & 3;      // 2 x 4 waves, 128x64 per wave
    const int l31 = lane & 31;
    const int lane16 = lane << 4;

    // bijective XCD swizzle (2048 % 8 == 0); n-chunked for B-slab L2 residency
    const int xcd = blockIdx.x & 7;
    const int c   = blockIdx.x >> 3;              // 0..255
    const int bn  = xcd * 8 + (c >> 5);           // 0..63
    const int bm  = c & 31;                       // 0..31
    const int bm2 = bm * 2, bn2 = bn * 2;

    const int woff16 = wave * 1024 + lane16;      // per-lane global offset
    const int woffu  = wave * 1024;               // wave-uniform LDS offset
    const int aoff = wm * 8192 + lane16;          // wave's A half-panel base
    const int boff = 16384 + (wn >> 1) * 8192 + (wn & 1) * 4096 + lane16;

    f32x16 acc[8] = {};   // [mb 0..3][nf 0..1]

    // prologue: stage tile0->L0, tile1->L1; retire tile0 (vmcnt(4)); sync
    STAGE_TILE(0, L0);
    STAGE_TILE(1, L1);
    asm volatile("s_waitcnt vmcnt(4)" ::: "memory");
    SB0();
    __builtin_amdgcn_s_barrier();
    SB0();

    for (int i = 0; i < 32; ++i) {
        const int T = i * 4;
        const bool nl = (i < 31);
        BODY(T + 0, L0, true, L2);
        BODY(T + 1, L1, true, L3);
        BODY(T + 2, L2, nl,   L0);
        BODY(T + 3, L3, nl,   L1);
    }

    // epilogue: 32x32 C/D: col=lane&31, row=(reg&3)+8*(reg>>2)+4*(lane>>5)
    // nontemporal: keep the 512MB C-stream out of L2/L3 (panels stay resident)
    const int rbase = bm * 256 + wm * 128 + (lane >> 5) * 4;
    const int cbase = bn * 256 + wn * 64 + l31;
    #pragma unroll
    for (int mb = 0; mb < 4; ++mb)
        #pragma unroll
        for (int nf = 0; nf < 2; ++nf)
            #pragma unroll
            for (int reg = 0; reg < 16; ++reg) {
                const int row = rbase + mb * 32 + (reg & 3) + 8 * (reg >> 2);
                __builtin_nontemporal_store(
                    acc[mb * 2 + nf][reg],
                    &out[(size_t)row * NTOT + cbase + nf * 32]);
            }
}

// ---------------- Fallback (ws too small): round-1 fused kernel ----------------
#define LDP 72
__global__ __launch_bounds__(256) void int4_gemm(
    const float* __restrict__ x, const int* __restrict__ qw,
    const int* __restrict__ qz, const float* __restrict__ sc,
    float* __restrict__ out)
{
    __shared__ short As[128][LDP];
    __shared__ short Bs[128][LDP];
    const int t = threadIdx.x;
    int gid = (blockIdx.x & 7) * 1024 + (blockIdx.x >> 3);
    const int bm = gid & 63;
    const int bnq = gid >> 6;
    const int kse = bnq >> 6;
    const int f0  = (bnq & 63) * 128;
    const int m0  = bm * 128;
    const int wave = t >> 6, lane = t & 63;
    const int wm = wave >> 1, wn = wave & 1;
    const int l15 = lane & 15, lhi = lane >> 4;
    const int am = t >> 4, ad = (t & 15) * 4;
    const int bf = t & 127, bd = (t >> 7) * 4;
    const int*   qwk = qw + (size_t)kse * Dd * Ff;
    const int*   qzk = qz + (size_t)kse * 32 * Ff;
    const float* sck = sc + (size_t)kse * 32 * Ff;
    f32x4 acc[4][4] = {};
    for (int d0 = 0; d0 < Dd; d0 += 64) {
        __syncthreads();
        #pragma unroll
        for (int p = 0; p < 8; ++p) {
            int m = p * 16 + am;
            const float4 v = *reinterpret_cast<const float4*>(
                &x[(size_t)(m0 + m) * Dd + d0 + ad]);
            short4 wv;
            wv.x = f2bf(v.x); wv.y = f2bf(v.y); wv.z = f2bf(v.z); wv.w = f2bf(v.w);
            *reinterpret_cast<short4*>(&As[m][ad]) = wv;
        }
        {
            const int g = d0 >> 7;
            const int   zv = qzk[g * Ff + f0 + bf];
            const float sv = sck[g * Ff + f0 + bf];
            #pragma unroll
            for (int p = 0; p < 8; ++p) {
                int dl = p * 8 + bd;
                const int* qp = qwk + (size_t)(d0 + dl) * Ff + f0 + bf;
                short4 wv;
                wv.x = f2bf((float)(qp[0]      - zv) * sv);
                wv.y = f2bf((float)(qp[Ff]     - zv) * sv);
                wv.z = f2bf((float)(qp[2 * Ff] - zv) * sv);
                wv.w = f2bf((float)(qp[3 * Ff] - zv) * sv);
                *reinterpret_cast<short4*>(&Bs[bf][dl]) = wv;
            }
        }
        __syncthreads();
        #pragma unroll
        for (int kk = 0; kk < 64; kk += 32) {
            bf16x8 a2[4], b2[4];
            #pragma unroll
            for (int i = 0; i < 4; ++i)
                a2[i] = *reinterpret_cast<const bf16x8*>(&As[wm * 64 + i * 16 + l15][kk + lhi * 8]);
            #pragma unroll
            for (int i = 0; i < 4; ++i)
                b2[i] = *reinterpret_cast<const bf16x8*>(&Bs[wn * 64 + i * 16 + l15][kk + lhi * 8]);
            #pragma unroll
            for (int mi = 0; mi < 4; ++mi)
                #pragma unroll
                for (int ni = 0; ni < 4; ++ni)
                    acc[mi][ni] = __builtin_amdgcn_mfma_f32_16x16x32_bf16(
                        a2[mi], b2[ni], acc[mi][ni], 0, 0, 0);
        }
    }
    const int crow0 = m0 + wm * 64 + lhi * 4;
    const int ccol0 = bnq * 128 + wn * 64 + l15;
    #pragma unroll
    for (int mi = 0; mi < 4; ++mi)
        #pragma unroll
        for (int ni = 0; ni < 4; ++ni)
            #pragma unroll
            for (int r = 0; r < 4; ++r)
                out[(size_t)(crow0 + mi * 16 + r) * NTOT + ccol0 + ni * 16] =
                    acc[mi][ni][r];
}

extern "C" void kernel_launch(void* const* d_in, const int* in_sizes, int n_in,
                              void* d_out, int out_size, void* d_ws, size_t ws_size,
                              hipStream_t stream) {
    const float* x  = (const float*)d_in[0];
    const int*   qw = (const int*)d_in[1];
    const int*   qz = (const int*)d_in[2];
    const float* sc = (const float*)d_in[3];
    float*       out = (float*)d_out;

    const size_t xw_bytes = (size_t)(M / 128) * NKT2 * 8192;      // 64 MiB
    const size_t ww_bytes = (size_t)(NTOT / 128) * NKT2 * 8192;   // 128 MiB

    if (ws_size >= xw_bytes + ww_bytes) {
        char* Xw = (char*)d_ws;
        char* Ww = Xw + xw_bytes;
        hipLaunchKernelGGL(xcvt, dim3((M / 128) * NKT2), dim3(256), 0, stream, x, Xw);
        hipLaunchKernelGGL(wdq, dim3((NTOT / 128) * NKT2), dim3(256), 0, stream,
                           qw, qz, sc, Ww);
        hipLaunchKernelGGL(gemm256, dim3(NMB * NNB), dim3(512), 0, stream,
                           Xw, Ww, out);
    } else {
        hipLaunchKernelGGL(int4_gemm, dim3(8192), dim3(256), 0, stream,
                           x, qw, qz, sc, out);
    }
}